// Round 5
// baseline (309.192 us; speedup 1.0000x reference)
//
#include <hip/hip_runtime.h>
#include <hip/hip_bf16.h>
#include <math.h>

#define B_  64
#define NS  512
#define NR  256
#define DD  1024
#define NEGV (-1e10f)

typedef __attribute__((ext_vector_type(4))) float f32x4;
typedef __attribute__((ext_vector_type(8))) short bf16x8;

__device__ __forceinline__ unsigned short f2bf(float x) {
    unsigned u = __builtin_bit_cast(unsigned, x);
    unsigned r = u + 0x7FFFu + ((u >> 16) & 1u);
    return (unsigned short)(r >> 16);
}
// packed bf16 convert: D.lo = bf16(x), D.hi = bf16(y)
__device__ __forceinline__ unsigned pk2(float x, float y) {
    unsigned r;
    asm("v_cvt_pk_bf16_f32 %0, %1, %2" : "=v"(r) : "v"(x), "v"(y));
    return r;
}
__device__ __forceinline__ void pk_hilo(float x, float y, unsigned& h, unsigned& l) {
    h = pk2(x, y);
    const float hx = __builtin_bit_cast(float, h << 16);
    const float hy = __builtin_bit_cast(float, h & 0xFFFF0000u);
    l = pk2(x - hx, y - hy);
}
// async global->LDS, 16B per lane
__device__ __forceinline__ void gload16(const void* g, void* l) {
    __builtin_amdgcn_global_load_lds((const __attribute__((address_space(1))) void*)g,
                                     (__attribute__((address_space(3))) void*)l, 16, 0, 0);
}

// ---------------------------------------------------------------- zero ws
__global__ __launch_bounds__(64) void zero_ws(double* ws) {
    if (threadIdx.x == 0) { ws[0] = 0.0; ws[1] = 0.0; }
}

// ================================================================ stage 1
// att = masked span @ image^T, bf16 hi/lo 3-pass MFMA, 128x128 tile.
// r3 schedule {load+convert+store; sync; MFMA; sync} + XOR-swizzled LDS
// (elem (r,k) at short ((k>>3)^(r&3))*8 + (k&7), rows 64B) + setprio +
// fused partial softmax stats.
__global__ __launch_bounds__(256) void att_mfma(
    const float* __restrict__ span, const float* __restrict__ image,
    const int* __restrict__ smask, const int* __restrict__ imask,
    float* __restrict__ att, float2* __restrict__ rowP, float2* __restrict__ colP,
    int doStats) {
    const int b  = blockIdx.z;
    const int s0 = blockIdx.y * 128;
    const int r0 = blockIdx.x * 128;
    __shared__ unsigned short Ah[128][32], Al[128][32], Bh[128][32], Bl[128][32];
    __shared__ float2 rowLDS[128][2];
    __shared__ float2 colLDS[128][2];
    const int tid  = threadIdx.x;
    const int lane = tid & 63;
    const int w    = tid >> 6;
    const int wso  = (w >> 1) * 64;
    const int wro  = (w & 1) * 64;
    const float* Sp = span  + ((size_t)b * NS + s0) * DD;
    const float* Im = image + ((size_t)b * NR + r0) * DD;

    f32x4 acc[4][4];
    #pragma unroll
    for (int i = 0; i < 4; ++i)
        #pragma unroll
        for (int j = 0; j < 4; ++j) acc[i][j] = (f32x4){0.f, 0.f, 0.f, 0.f};

    const int j8   = tid & 7;          // 0..7 : k-chunk within row
    const int row0 = tid >> 3;         // 0..31
    const int krel = j8 * 4;
    const int fr   = lane & 15;
    const int fq   = lane >> 4;

    for (int k0 = 0; k0 < DD; k0 += 32) {
        #pragma unroll
        for (int p = 0; p < 4; ++p) {
            const int row = row0 + p * 32;
            const int wp  = (((j8 >> 1) ^ (row & 3)) << 3) + ((j8 & 1) << 2);  // short idx
            const float4 a = *reinterpret_cast<const float4*>(Sp + (size_t)row * DD + k0 + krel);
            const float4 c = *reinterpret_cast<const float4*>(Im + (size_t)row * DD + k0 + krel);
            unsigned h0, l0, h1, l1;
            uint2 u;
            pk_hilo(a.x, a.y, h0, l0); pk_hilo(a.z, a.w, h1, l1);
            u.x = h0; u.y = h1; *reinterpret_cast<uint2*>(&Ah[row][wp]) = u;
            u.x = l0; u.y = l1; *reinterpret_cast<uint2*>(&Al[row][wp]) = u;
            pk_hilo(c.x, c.y, h0, l0); pk_hilo(c.z, c.w, h1, l1);
            u.x = h0; u.y = h1; *reinterpret_cast<uint2*>(&Bh[row][wp]) = u;
            u.x = l0; u.y = l1; *reinterpret_cast<uint2*>(&Bl[row][wp]) = u;
        }
        __syncthreads();
        bf16x8 ah[4], al[4], bh[4], bl[4];
        #pragma unroll
        for (int mf = 0; mf < 4; ++mf) {
            const int ra = wso + mf * 16 + fr;
            const int pa_ = (fq ^ (ra & 3)) << 3;
            ah[mf] = *reinterpret_cast<const bf16x8*>(&Ah[ra][pa_]);
            al[mf] = *reinterpret_cast<const bf16x8*>(&Al[ra][pa_]);
            const int rb = wro + mf * 16 + fr;
            const int pb_ = (fq ^ (rb & 3)) << 3;
            bh[mf] = *reinterpret_cast<const bf16x8*>(&Bh[rb][pb_]);
            bl[mf] = *reinterpret_cast<const bf16x8*>(&Bl[rb][pb_]);
        }
        __builtin_amdgcn_s_setprio(1);
        #pragma unroll
        for (int mf = 0; mf < 4; ++mf)
            #pragma unroll
            for (int nf = 0; nf < 4; ++nf) {
                acc[mf][nf] = __builtin_amdgcn_mfma_f32_16x16x32_bf16(ah[mf], bh[nf], acc[mf][nf], 0, 0, 0);
                acc[mf][nf] = __builtin_amdgcn_mfma_f32_16x16x32_bf16(ah[mf], bl[nf], acc[mf][nf], 0, 0, 0);
                acc[mf][nf] = __builtin_amdgcn_mfma_f32_16x16x32_bf16(al[mf], bh[nf], acc[mf][nf], 0, 0, 0);
            }
        __builtin_amdgcn_s_setprio(0);
        __syncthreads();
    }

    // ---- epilogue: mask + zero->NEG store, fused partial softmax stats
    const int fq4 = lane >> 4;
    float imvf[4];
    #pragma unroll
    for (int nf = 0; nf < 4; ++nf) imvf[nf] = (float)imask[b * NR + r0 + wro + nf * 16 + fr];
    float cmax[4] = {-3.4e38f, -3.4e38f, -3.4e38f, -3.4e38f};
    float smv[4][4];
    #pragma unroll
    for (int mf = 0; mf < 4; ++mf) {
        #pragma unroll
        for (int i = 0; i < 4; ++i) {
            const int s = s0 + wso + mf * 16 + fq4 * 4 + i;
            const float sv = (float)smask[b * NS + s];
            smv[mf][i] = sv;
            float* orow = att + ((size_t)b * NS + s) * NR + r0 + wro;
            float vj[4];
            #pragma unroll
            for (int nf = 0; nf < 4; ++nf) {
                float v = acc[mf][nf][i] * (sv * imvf[nf]);
                v = (v != 0.0f) ? v : NEGV;
                orow[nf * 16 + fr] = v;
                vj[nf] = v;
                cmax[nf] = fmaxf(cmax[nf], v);
            }
            if (doStats) {
                float rm = fmaxf(fmaxf(vj[0], vj[1]), fmaxf(vj[2], vj[3]));
                rm = fmaxf(rm, __shfl_xor(rm, 1));
                rm = fmaxf(rm, __shfl_xor(rm, 2));
                rm = fmaxf(rm, __shfl_xor(rm, 4));
                rm = fmaxf(rm, __shfl_xor(rm, 8));
                float rs = expf(vj[0] - rm) + expf(vj[1] - rm) + expf(vj[2] - rm) + expf(vj[3] - rm);
                rs += __shfl_xor(rs, 1);
                rs += __shfl_xor(rs, 2);
                rs += __shfl_xor(rs, 4);
                rs += __shfl_xor(rs, 8);
                if (fr == 0) rowLDS[wso + mf * 16 + fq4 * 4 + i][w & 1] = make_float2(rm, rs);
            }
        }
    }
    if (doStats) {
        #pragma unroll
        for (int nf = 0; nf < 4; ++nf) {
            cmax[nf] = fmaxf(cmax[nf], __shfl_xor(cmax[nf], 16));
            cmax[nf] = fmaxf(cmax[nf], __shfl_xor(cmax[nf], 32));
        }
        float csum[4] = {0.f, 0.f, 0.f, 0.f};
        #pragma unroll
        for (int mf = 0; mf < 4; ++mf)
            #pragma unroll
            for (int i = 0; i < 4; ++i)
                #pragma unroll
                for (int nf = 0; nf < 4; ++nf) {
                    float v = acc[mf][nf][i] * (smv[mf][i] * imvf[nf]);
                    v = (v != 0.0f) ? v : NEGV;
                    csum[nf] += expf(v - cmax[nf]);
                }
        #pragma unroll
        for (int nf = 0; nf < 4; ++nf) {
            csum[nf] += __shfl_xor(csum[nf], 16);
            csum[nf] += __shfl_xor(csum[nf], 32);
        }
        if (lane < 16) {
            #pragma unroll
            for (int nf = 0; nf < 4; ++nf)
                colLDS[wro + nf * 16 + lane][w >> 1] = make_float2(cmax[nf], csum[nf]);
        }
        __syncthreads();
        if (tid < 128) {
            const float2 q0 = rowLDS[tid][0], q1 = rowLDS[tid][1];
            const float m = fmaxf(q0.x, q1.x);
            const float ssum = q0.y * expf(q0.x - m) + q1.y * expf(q1.x - m);
            rowP[((size_t)b * NS + s0 + tid) * 2 + blockIdx.x] = make_float2(m, ssum);
        } else {
            const int c = tid - 128;
            const float2 q0 = colLDS[c][0], q1 = colLDS[c][1];
            const float m = fmaxf(q0.x, q1.x);
            const float ssum = q0.y * expf(q0.x - m) + q1.y * expf(q1.x - m);
            colP[((size_t)b * NR + r0 + c) * 4 + blockIdx.y] = make_float2(m, ssum);
        }
    }
}

// ================================================================ combine partials -> m1,f1 (rows), m2,f2 (cols)
__global__ __launch_bounds__(256) void combine_stats(
    const float2* __restrict__ rowP, const float2* __restrict__ colP,
    const int* __restrict__ smask, const int* __restrict__ imask,
    float* __restrict__ m1, float* __restrict__ f1,
    float* __restrict__ m2, float* __restrict__ f2) {
    const int idx = blockIdx.x * 256 + threadIdx.x;
    if (idx < B_ * NS) {
        const float2 p0 = rowP[(size_t)idx * 2 + 0];
        const float2 p1 = rowP[(size_t)idx * 2 + 1];
        const float m = fmaxf(p0.x, p1.x);
        const float s = p0.y * expf(p0.x - m) + p1.y * expf(p1.x - m);
        m1[idx] = m;
        f1[idx] = (float)smask[idx] / s;
    } else if (idx < B_ * NS + B_ * NR) {
        const int j = idx - B_ * NS;
        const float2 p0 = colP[(size_t)j * 4 + 0];
        const float2 p1 = colP[(size_t)j * 4 + 1];
        const float2 p2 = colP[(size_t)j * 4 + 2];
        const float2 p3 = colP[(size_t)j * 4 + 3];
        const float m = fmaxf(fmaxf(p0.x, p1.x), fmaxf(p2.x, p3.x));
        const float s = p0.y * expf(p0.x - m) + p1.y * expf(p1.x - m)
                      + p2.y * expf(p2.x - m) + p3.y * expf(p3.x - m);
        m2[j] = m;
        f2[j] = (float)imask[j] / s;
    }
}

// ================================================================ transpose f32 -> bf16, K-swizzled within 64-chunks by (d&7)<<3
__global__ __launch_bounds__(256) void transpose_swz(
    const float* __restrict__ src, unsigned short* __restrict__ dst, int N) {
    const int b = blockIdx.z, n0 = blockIdx.y * 32, d0 = blockIdx.x * 32;
    __shared__ unsigned short T[32][36];
    const int t = threadIdx.x;
    {
        const int n = t >> 3, dq = (t & 7) * 4;
        const float4 v = *reinterpret_cast<const float4*>(src + ((size_t)b * N + n0 + n) * DD + d0 + dq);
        T[dq + 0][n] = f2bf(v.x); T[dq + 1][n] = f2bf(v.y);
        T[dq + 2][n] = f2bf(v.z); T[dq + 3][n] = f2bf(v.w);
    }
    __syncthreads();
    {
        const int d = t >> 3, nq = (t & 7) * 4;
        const int dg = d0 + d;
        const int base = n0 + nq;
        const int pos = (base & 63) ^ ((dg & 7) << 3);
        const size_t idx = ((size_t)b * DD + dg) * N + (base & ~63) + pos;
        *reinterpret_cast<ushort4*>(dst + idx) = *reinterpret_cast<const ushort4*>(&T[d][nq]);
    }
}

// ================================================================ build w1 ([s][r], swizzled) AND w2 ([r][s], swizzled) in one att pass
__global__ __launch_bounds__(256) void build_w12(
    const float* __restrict__ att, const int* __restrict__ smask,
    const int* __restrict__ imask,
    const float* __restrict__ m1, const float* __restrict__ f1,
    const float* __restrict__ m2, const float* __restrict__ f2,
    unsigned short* __restrict__ w1g, unsigned short* __restrict__ w2g) {
    const int b = blockIdx.z, s0 = blockIdx.y * 64, r0 = blockIdx.x * 64;
    __shared__ unsigned short T[64][68];
    __shared__ float m2s[64], f2s[64], ims[64];
    const int tid = threadIdx.x;
    if (tid < 64) {
        m2s[tid] = m2[b * NR + r0 + tid];
        f2s[tid] = f2[b * NR + r0 + tid];
        ims[tid] = (float)imask[b * NR + r0 + tid];
    }
    __syncthreads();
    {
        const int srow = tid >> 2, rg = (tid & 3) * 16;
        const int s = s0 + srow;
        const float m1v = m1[b * NS + s], f1v = f1[b * NS + s];
        const float smv = (float)smask[b * NS + s];
        const float* arow = att + ((size_t)b * NS + s) * NR + r0;
        const int w1swz = (s & 7) << 3;
        unsigned short* w1row = w1g + ((size_t)b * NS + s) * NR + r0;
        #pragma unroll
        for (int g = 0; g < 4; ++g) {
            const int rr = rg + g * 4;
            const float4 a = *reinterpret_cast<const float4*>(arow + rr);
            // w1 = exp(a - m1[s]) * f1[s] * im[r]
            const float e0 = expf(a.x - m1v) * f1v * ims[rr + 0];
            const float e1 = expf(a.y - m1v) * f1v * ims[rr + 1];
            const float e2 = expf(a.z - m1v) * f1v * ims[rr + 2];
            const float e3 = expf(a.w - m1v) * f1v * ims[rr + 3];
            uint2 u; u.x = pk2(e0, e1); u.y = pk2(e2, e3);
            *reinterpret_cast<uint2*>(w1row + (rr ^ w1swz)) = u;
            // w2 = exp(a - m2[r]) * f2[r] * sm[s]  -> transposed via LDS
            const float q0 = expf(a.x - m2s[rr + 0]) * f2s[rr + 0] * smv;
            const float q1 = expf(a.y - m2s[rr + 1]) * f2s[rr + 1] * smv;
            const float q2 = expf(a.z - m2s[rr + 2]) * f2s[rr + 2] * smv;
            const float q3 = expf(a.w - m2s[rr + 3]) * f2s[rr + 3] * smv;
            const unsigned t0 = pk2(q0, q1), t1 = pk2(q2, q3);
            T[rr + 0][srow] = (unsigned short)(t0 & 0xFFFF);
            T[rr + 1][srow] = (unsigned short)(t0 >> 16);
            T[rr + 2][srow] = (unsigned short)(t1 & 0xFFFF);
            T[rr + 3][srow] = (unsigned short)(t1 >> 16);
        }
    }
    __syncthreads();
    {
        const int rl = tid >> 2, sg = (tid & 3) * 16;
        const int w2swz = (rl & 7) << 3;
        unsigned short* w2row = w2g + ((size_t)b * NR + r0 + rl) * NS + s0;
        #pragma unroll
        for (int g = 0; g < 4; ++g) {
            const int ss = sg + g * 4;
            *reinterpret_cast<ushort4*>(w2row + (ss ^ w2swz)) =
                *reinterpret_cast<const ushort4*>(&T[rl][ss]);
        }
    }
}

// ================================================================ apply GEMM: C[64 m x 256 d] = A[m][K] @ Bt[d][K] (both pre-swizzled bf16)
template<int KTOT, int MT, bool WOUT, int WIDX>
__global__ __launch_bounds__(256) void gemm_apply(
    const unsigned short* __restrict__ Ag, const unsigned short* __restrict__ Btg,
    const float* __restrict__ ref, float* __restrict__ outp, double* __restrict__ wsum) {
    const int b = blockIdx.z, m0 = blockIdx.y * 64, d0 = blockIdx.x * 256;
    __shared__ unsigned short As[64 * 64];
    __shared__ unsigned short Bs[256 * 64];
    __shared__ float redsum[256];
    const int tid = threadIdx.x, lane = tid & 63, w = tid >> 6;
    const int fr = lane & 15, fq = lane >> 4;
    f32x4 acc[4][4];
    #pragma unroll
    for (int i = 0; i < 4; ++i)
        #pragma unroll
        for (int j = 0; j < 4; ++j) acc[i][j] = (f32x4){0.f, 0.f, 0.f, 0.f};

    const int srow = tid >> 3;             // 0..31 staging row
    const int scol = (tid & 7) * 16;       // byte offset in 128B chunk
    for (int kc = 0; kc < KTOT / 64; ++kc) {
        const char* asrc = (const char*)(Ag + ((size_t)b * MT + m0) * KTOT) + kc * 128 + scol;
        #pragma unroll
        for (int c = 0; c < 2; ++c)
            gload16(asrc + (size_t)(c * 32 + srow) * (KTOT * 2), (char*)As + (c * 256 + tid) * 16);
        const char* bsrc = (const char*)(Btg + ((size_t)b * DD + d0) * KTOT) + kc * 128 + scol;
        #pragma unroll
        for (int c = 0; c < 8; ++c)
            gload16(bsrc + (size_t)(c * 32 + srow) * (KTOT * 2), (char*)Bs + (c * 256 + tid) * 16);
        __syncthreads();
        #pragma unroll
        for (int ks = 0; ks < 2; ++ks) {
            bf16x8 aF[4], bF[4];
            #pragma unroll
            for (int mf = 0; mf < 4; ++mf) {
                const int row = mf * 16 + fr;
                const int pos = (ks * 32 + fq * 8) ^ ((row & 7) << 3);
                aF[mf] = *reinterpret_cast<const bf16x8*>(&As[row * 64 + pos]);
            }
            #pragma unroll
            for (int nf = 0; nf < 4; ++nf) {
                const int row = w * 64 + nf * 16 + fr;
                const int pos = (ks * 32 + fq * 8) ^ ((row & 7) << 3);
                bF[nf] = *reinterpret_cast<const bf16x8*>(&Bs[row * 64 + pos]);
            }
            #pragma unroll
            for (int mf = 0; mf < 4; ++mf)
                #pragma unroll
                for (int nf = 0; nf < 4; ++nf)
                    acc[mf][nf] = __builtin_amdgcn_mfma_f32_16x16x32_bf16(aF[mf], bF[nf], acc[mf][nf], 0, 0, 0);
        }
        __syncthreads();
    }
    float sumsq = 0.0f;
    #pragma unroll
    for (int mf = 0; mf < 4; ++mf) {
        #pragma unroll
        for (int i = 0; i < 4; ++i) {
            const int row = m0 + mf * 16 + fq * 4 + i;
            const size_t base = ((size_t)b * MT + row) * DD + d0 + w * 64;
            #pragma unroll
            for (int nf = 0; nf < 4; ++nf) {
                const float v = acc[mf][nf][i];
                const float rv = ref[base + nf * 16 + fr];
                if constexpr (WOUT) outp[base + nf * 16 + fr] = v;
                const float dx = rv - v;
                sumsq += dx * dx;
            }
        }
    }
    redsum[tid] = sumsq; __syncthreads();
    for (int off = 128; off; off >>= 1) {
        if (tid < off) redsum[tid] += redsum[tid + off];
        __syncthreads();
    }
    if (tid == 0) atomicAdd(wsum + WIDX, (double)redsum[0]);
}

// ================================================================ fallback f32 kernels (used when ws too small)
__global__ __launch_bounds__(256) void first_kernel(
    const float* __restrict__ span, const float* __restrict__ image,
    const int* __restrict__ smask, const int* __restrict__ imask,
    const float* __restrict__ att, float* __restrict__ att_first,
    double* __restrict__ ws) {
    const int b  = blockIdx.y;
    const int s0 = blockIdx.x * 32;
    __shared__ float wT[256][36];
    __shared__ float Is[32][132];
    __shared__ float red[256];
    const int tid  = threadIdx.x;
    const int lane = tid & 63, wave = tid >> 6;
    for (int i = 0; i < 8; ++i) {
        const int srel = wave * 8 + i;
        const int s    = s0 + srel;
        const float4 v = *reinterpret_cast<const float4*>(att + ((size_t)b * NS + s) * NR + lane * 4);
        float m = fmaxf(fmaxf(v.x, v.y), fmaxf(v.z, v.w));
        #pragma unroll
        for (int off = 32; off; off >>= 1) m = fmaxf(m, __shfl_xor(m, off));
        float4 e;
        e.x = expf(v.x - m); e.y = expf(v.y - m); e.z = expf(v.z - m); e.w = expf(v.w - m);
        float sum = e.x + e.y + e.z + e.w;
        #pragma unroll
        for (int off = 32; off; off >>= 1) sum += __shfl_xor(sum, off);
        const float fac = (float)smask[b * NS + s] / sum;
        const int4 im4 = *reinterpret_cast<const int4*>(imask + b * NR + lane * 4);
        wT[lane * 4 + 0][srel] = e.x * fac * (float)im4.x;
        wT[lane * 4 + 1][srel] = e.y * fac * (float)im4.y;
        wT[lane * 4 + 2][srel] = e.z * fac * (float)im4.z;
        wT[lane * 4 + 3][srel] = e.w * fac * (float)im4.w;
    }
    __syncthreads();
    float sumsq = 0.0f;
    const int txd = tid & 31;
    const int tys = tid >> 5;
    const float* Ib = image + (size_t)b * NR * DD;
    for (int dc = 0; dc < 8; ++dc) {
        const int d0 = dc * 128;
        float acc[4][4] = {};
        for (int rc = 0; rc < 8; ++rc) {
            const int r0 = rc * 32;
            {
                const int rr = tid >> 3;
                const int cb = tid & 7;
                const float* src = Ib + (size_t)(r0 + rr) * DD + d0;
                #pragma unroll
                for (int q = 0; q < 4; ++q)
                    *reinterpret_cast<float4*>(&Is[rr][(cb + 8 * q) * 4]) =
                        *reinterpret_cast<const float4*>(src + (cb + 8 * q) * 4);
            }
            __syncthreads();
            #pragma unroll 4
            for (int rr = 0; rr < 32; ++rr) {
                const float4 wv = *reinterpret_cast<const float4*>(&wT[r0 + rr][tys * 4]);
                const float4 iv = *reinterpret_cast<const float4*>(&Is[rr][txd * 4]);
                const float wvv[4] = {wv.x, wv.y, wv.z, wv.w};
                const float ivv[4] = {iv.x, iv.y, iv.z, iv.w};
                #pragma unroll
                for (int i = 0; i < 4; ++i)
                    #pragma unroll
                    for (int j = 0; j < 4; ++j)
                        acc[i][j] += wvv[i] * ivv[j];
            }
            __syncthreads();
        }
        #pragma unroll
        for (int i = 0; i < 4; ++i) {
            const int s = s0 + tys * 4 + i;
            const size_t base = ((size_t)b * NS + s) * DD + d0 + txd * 4;
            const float4 af = {acc[i][0], acc[i][1], acc[i][2], acc[i][3]};
            *reinterpret_cast<float4*>(att_first + base) = af;
            const float4 sp = *reinterpret_cast<const float4*>(span + base);
            float dx;
            dx = sp.x - af.x; sumsq += dx * dx;
            dx = sp.y - af.y; sumsq += dx * dx;
            dx = sp.z - af.z; sumsq += dx * dx;
            dx = sp.w - af.w; sumsq += dx * dx;
        }
    }
    red[tid] = sumsq; __syncthreads();
    for (int off = 128; off; off >>= 1) {
        if (tid < off) red[tid] += red[tid + off];
        __syncthreads();
    }
    if (tid == 0) atomicAdd(ws, (double)red[0]);
}

__global__ __launch_bounds__(256) void second_kernel(
    const float* __restrict__ span, const float* __restrict__ image,
    const int* __restrict__ smask, const int* __restrict__ imask,
    const float* __restrict__ att, double* __restrict__ ws) {
    const int b  = blockIdx.y;
    const int r0 = blockIdx.x * 32;
    __shared__ float w2s[32][36];
    __shared__ float Ss[32][132];
    __shared__ float mArr[32], fArr[32];
    __shared__ float redm[8][32];
    __shared__ float red[256];
    const int tid = threadIdx.x;
    const int rr = tid & 31, q = tid >> 5;
    const float* attb = att + (size_t)b * NS * NR + r0 + rr;
    float mloc = -3.4e38f;
    for (int t = 0; t < 64; ++t)
        mloc = fmaxf(mloc, attb[(size_t)(q * 64 + t) * NR]);
    redm[q][rr] = mloc;
    __syncthreads();
    if (tid < 32) {
        float m = redm[0][tid];
        #pragma unroll
        for (int qq = 1; qq < 8; ++qq) m = fmaxf(m, redm[qq][tid]);
        mArr[tid] = m;
    }
    __syncthreads();
    const float mcol = mArr[rr];
    float sloc = 0.0f;
    for (int t = 0; t < 64; ++t)
        sloc += expf(attb[(size_t)(q * 64 + t) * NR] - mcol);
    redm[q][rr] = sloc;
    __syncthreads();
    if (tid < 32) {
        float s = 0.0f;
        #pragma unroll
        for (int qq = 0; qq < 8; ++qq) s += redm[qq][tid];
        fArr[tid] = (float)imask[b * NR + r0 + tid] / s;
    }
    __syncthreads();
    float sumsq = 0.0f;
    const int txd = tid & 31;
    const int tyr = tid >> 5;
    const float* Sb = span + (size_t)b * NS * DD;
    for (int dc = 0; dc < 8; ++dc) {
        const int d0 = dc * 128;
        float acc[4][4] = {};
        for (int sc = 0; sc < 16; ++sc) {
            const int sb0 = sc * 32;
            {
                const int sr = tid >> 3;
                const int cb = tid & 7;
                const float* src = Sb + (size_t)(sb0 + sr) * DD + d0;
                #pragma unroll
                for (int qq = 0; qq < 4; ++qq)
                    *reinterpret_cast<float4*>(&Ss[sr][(cb + 8 * qq) * 4]) =
                        *reinterpret_cast<const float4*>(src + (cb + 8 * qq) * 4);
            }
            {
                const int ss = tid >> 3;
                const int rq = (tid & 7) * 4;
                const int s  = sb0 + ss;
                const float4 v = *reinterpret_cast<const float4*>(att + ((size_t)b * NS + s) * NR + r0 + rq);
                const float smv = (float)smask[b * NS + s];
                float4 wv;
                wv.x = expf(v.x - mArr[rq + 0]) * fArr[rq + 0] * smv;
                wv.y = expf(v.y - mArr[rq + 1]) * fArr[rq + 1] * smv;
                wv.z = expf(v.z - mArr[rq + 2]) * fArr[rq + 2] * smv;
                wv.w = expf(v.w - mArr[rq + 3]) * fArr[rq + 3] * smv;
                *reinterpret_cast<float4*>(&w2s[ss][rq]) = wv;
            }
            __syncthreads();
            #pragma unroll 4
            for (int ss = 0; ss < 32; ++ss) {
                const float4 wv = *reinterpret_cast<const float4*>(&w2s[ss][tyr * 4]);
                const float4 sv = *reinterpret_cast<const float4*>(&Ss[ss][txd * 4]);
                const float wvv[4] = {wv.x, wv.y, wv.z, wv.w};
                const float svv[4] = {sv.x, sv.y, sv.z, sv.w};
                #pragma unroll
                for (int i = 0; i < 4; ++i)
                    #pragma unroll
                    for (int j = 0; j < 4; ++j)
                        acc[i][j] += wvv[i] * svv[j];
            }
            __syncthreads();
        }
        #pragma unroll
        for (int i = 0; i < 4; ++i) {
            const int r = r0 + tyr * 4 + i;
            const float4 iv = *reinterpret_cast<const float4*>(image + ((size_t)b * NR + r) * DD + d0 + txd * 4);
            float dx;
            dx = iv.x - acc[i][0]; sumsq += dx * dx;
            dx = iv.y - acc[i][1]; sumsq += dx * dx;
            dx = iv.z - acc[i][2]; sumsq += dx * dx;
            dx = iv.w - acc[i][3]; sumsq += dx * dx;
        }
    }
    red[tid] = sumsq; __syncthreads();
    for (int off = 128; off; off >>= 1) {
        if (tid < off) red[tid] += red[tid + off];
        __syncthreads();
    }
    if (tid == 0) atomicAdd(ws + 1, (double)red[0]);
}

// ---------------------------------------------------------------- final score
__global__ __launch_bounds__(64) void score_kernel(const double* __restrict__ ws, float* __restrict__ out) {
    if (threadIdx.x == 0) {
        out[0] = (float)(ws[0] / (double)((size_t)B_ * NS * DD) +
                         ws[1] / (double)((size_t)B_ * NR * DD));
    }
}

extern "C" void kernel_launch(void* const* d_in, const int* in_sizes, int n_in,
                              void* d_out, int out_size, void* d_ws, size_t ws_size,
                              hipStream_t stream) {
    const float* span  = (const float*)d_in[0];
    const float* image = (const float*)d_in[1];
    const int*   smask = (const int*)d_in[2];
    const int*   imask = (const int*)d_in[3];
    float* out       = (float*)d_out;
    float* att_first = out + 1;
    float* att       = out + 1 + (size_t)B_ * NS * DD;

    // ws layout:
    //  wsum(512B) | m1,f1 (B*NS f32 each) | m2,f2 (B*NR f32 each)
    //  | rowP (B*NS*2 float2) | colP (B*NR*4 float2)
    //  | X0: imgT [0,32M) , w1 [32M,48M)  -> phase 1
    //        spT  [0,64M)                 -> phase 2 (overwrites imgT,w1)
    //        w2   [64M,80M)               -> live across both
    char* base = (char*)d_ws;
    double* wsum = (double*)base;
    float* m1 = (float*)(base + 512);
    float* f1 = m1 + (size_t)B_ * NS;
    float* m2 = f1 + (size_t)B_ * NS;
    float* f2 = m2 + (size_t)B_ * NR;
    float2* rowP = (float2*)(f2 + (size_t)B_ * NR);
    float2* colP = rowP + (size_t)B_ * NS * 2;
    char* X0 = (char*)(colP + (size_t)B_ * NR * 4);
    unsigned short* imgT = (unsigned short*)X0;
    unsigned short* w1g  = (unsigned short*)(X0 + (size_t)B_ * DD * NR * 2);
    unsigned short* spT  = (unsigned short*)X0;
    unsigned short* w2g  = (unsigned short*)(X0 + (size_t)B_ * DD * NS * 2);
    const size_t NEED = (size_t)(X0 - base) + (size_t)B_ * DD * NS * 2 + (size_t)B_ * NS * NR * 2;
    const int wsok = (ws_size >= NEED) ? 1 : 0;

    zero_ws<<<dim3(1), dim3(64), 0, stream>>>(wsum);
    att_mfma<<<dim3(NR / 128, NS / 128, B_), dim3(256), 0, stream>>>(
        span, image, smask, imask, att, rowP, colP, wsok);

    if (wsok) {
        combine_stats<<<dim3((B_ * NS + B_ * NR) / 256), dim3(256), 0, stream>>>(
            rowP, colP, smask, imask, m1, f1, m2, f2);
        transpose_swz<<<dim3(DD / 32, NR / 32, B_), dim3(256), 0, stream>>>(image, imgT, NR);
        build_w12<<<dim3(NR / 64, NS / 64, B_), dim3(256), 0, stream>>>(
            att, smask, imask, m1, f1, m2, f2, w1g, w2g);
        gemm_apply<NR, NS, true, 0><<<dim3(DD / 256, NS / 64, B_), dim3(256), 0, stream>>>(
            w1g, imgT, span, att_first, wsum);
        transpose_swz<<<dim3(DD / 32, NS / 32, B_), dim3(256), 0, stream>>>(span, spT, NS);
        gemm_apply<NS, NR, false, 1><<<dim3(DD / 256, NR / 64, B_), dim3(256), 0, stream>>>(
            w2g, spT, image, nullptr, wsum);
    } else {
        first_kernel<<<dim3(NS / 32, B_), dim3(256), 0, stream>>>(span, image, smask, imask, att, att_first, wsum);
        second_kernel<<<dim3(NR / 32, B_), dim3(256), 0, stream>>>(span, image, smask, imask, att, wsum);
    }
    score_kernel<<<dim3(1), dim3(64), 0, stream>>>(wsum, out);
}